// Round 8
// baseline (597.476 us; speedup 1.0000x reference)
//
#include <hip/hip_runtime.h>

#define BB 2
#define NN 4096
#define CC 256
#define FF 1024
#define NLAYER 4
#define RR (BB*NN)
#define SPL 16           // n/m split for attention passes
#define QKLD (3*CC)      // qkv packed row stride = 768
#define NEG_BIG (-1e30f)
#define LOG2E 1.44269504f

typedef _Float16 h16;
typedef __attribute__((ext_vector_type(8))) _Float16 half8;
typedef __attribute__((ext_vector_type(4))) float f32x4;
typedef __attribute__((ext_vector_type(16))) float f32x16;

#define WAITVM(n) asm volatile("s_waitcnt vmcnt(" #n ")" ::: "memory")

// ---------------- async global->LDS, 16B per lane ----------------
__device__ __forceinline__ void gload16(const h16* g, h16* l) {
    __builtin_amdgcn_global_load_lds((const __attribute__((address_space(1))) void*)g,
                                     (__attribute__((address_space(3))) void*)l, 16, 0, 0);
}

// stage ROWS x 64 h16 chunk into lds[ROWS][64] with piece-XOR swizzle (256 threads)
template<int ROWS>
__device__ __forceinline__ void stage_rows(const h16* __restrict__ src, int ld,
    int row0, int c0, h16* lds, int tid)
{
    int w = tid >> 6;
    #pragma unroll
    for (int t = 0; t < ROWS/32; ++t) {
        int slot = t*256 + tid;
        int row = slot >> 3;
        int pp  = slot & 7;
        int piece = pp ^ (row & 7);
        gload16(src + (size_t)(row0 + row)*ld + c0 + piece*8,
                lds + (t*256 + w*64)*8);    // wave-uniform base; HW adds lane*16B
    }
}

// read 8 contiguous h16 (logical k-piece pl) of LDS row
__device__ __forceinline__ half8 frag_ld(const h16* lds, int row, int pl) {
    return *(const half8*)(lds + row*64 + ((pl ^ (row & 7))*8));
}

// ---------------- weight transpose+convert: W[K,N] f32 -> WT[N,K] f16 (optional scale) ----------------
__global__ __launch_bounds__(256) void pct_wtrans(const float* __restrict__ W,
    h16* __restrict__ WT, int K, int N, int dstride, float scale)
{
    __shared__ h16 t[32][33];
    const float* Wl = W + (size_t)blockIdx.z*K*N;
    h16* WTl = WT + (size_t)blockIdx.z*dstride;
    int k0 = blockIdx.x*32, n0 = blockIdx.y*32;
    int tx = threadIdx.x & 31, ty = threadIdx.x >> 5;
    #pragma unroll
    for (int i = ty; i < 32; i += 8)
        t[i][tx] = (h16)(Wl[(size_t)(k0+i)*N + n0 + tx] * scale);
    __syncthreads();
    #pragma unroll
    for (int i = ty; i < 32; i += 8)
        WTl[(size_t)(n0+i)*K + k0 + tx] = t[tx][i];
}

// combined q/k/v transpose into packed [NLAYER][768][256]; q scaled by log2(e)
__global__ __launch_bounds__(256) void pct_wtrans_qkv(const float* __restrict__ wq,
    const float* __restrict__ wk, const float* __restrict__ wv, h16* __restrict__ WT)
{
    __shared__ h16 t[32][33];
    int z = blockIdx.z;
    int which = z >> 2, layer = z & 3;          // NLAYER == 4
    const float* Wl = (which == 0 ? wq : which == 1 ? wk : wv) + (size_t)layer*CC*CC;
    h16* WTl = WT + (size_t)layer*QKLD*CC + (size_t)which*CC*CC;
    float scale = (which == 0) ? LOG2E : 1.0f;
    int k0 = blockIdx.x*32, n0 = blockIdx.y*32;
    int tx = threadIdx.x & 31, ty = threadIdx.x >> 5;
    #pragma unroll
    for (int i = ty; i < 32; i += 8)
        t[i][tx] = (h16)(Wl[(size_t)(k0+i)*CC + n0 + tx] * scale);
    __syncthreads();
    #pragma unroll
    for (int i = ty; i < 32; i += 8)
        WTl[(size_t)(n0+i)*CC + k0 + tx] = t[tx][i];
}

// ---------------- pack q/k/v biases into [NLAYER][768]; q bias scaled by log2(e) ----------------
__global__ __launch_bounds__(256) void pct_bias3(const float* __restrict__ bq,
    const float* __restrict__ bk, const float* __restrict__ bv, float* __restrict__ o)
{
    int l = blockIdx.x, c = threadIdx.x;
    o[l*QKLD + c]        = bq[l*CC + c] * LOG2E;
    o[l*QKLD + CC + c]   = bk[l*CC + c];
    o[l*QKLD + 2*CC + c] = bv[l*CC + c];
}

// ---------------- embed + fused column stats ----------------
__global__ __launch_bounds__(256) void pct_embed(const float* __restrict__ inp,
    const float* __restrict__ w0, const float* __restrict__ b0,
    h16* __restrict__ out, float* __restrict__ sums)
{
    int c = threadIdx.x;
    int r0 = blockIdx.x * 64;
    float wa = w0[c], wb = w0[CC+c], wcv = w0[2*CC+c], bb = b0[c];
    float s1 = 0.f, s2 = 0.f;
    #pragma unroll 4
    for (int i = 0; i < 64; ++i) {
        int r = r0 + i;
        float y = bb + inp[r*3+0]*wa + inp[r*3+1]*wb + inp[r*3+2]*wcv;
        h16 hy = (h16)y;
        out[(size_t)r*CC + c] = hy;
        float yf = (float)hy;
        s1 += yf; s2 += yf*yf;
    }
    int b = r0 >> 12;
    atomicAdd(&sums[((size_t)b*CC + c)*2 + 0], s1);
    atomicAdd(&sums[((size_t)b*CC + c)*2 + 1], s2);
}

// ---------------- apply LN (stats over points), optional relu + residual ----------------
__global__ __launch_bounds__(256) void pct_lnapply(const h16* __restrict__ x, int ldx,
    const float* __restrict__ sums, const float* __restrict__ scale, const float* __restrict__ bias,
    const h16* __restrict__ res, int ldr, h16* __restrict__ out, int ldo,
    int do_relu)
{
    int r = blockIdx.x*8 + (threadIdx.x >> 5);
    int cg = (threadIdx.x & 31) * 8;
    int b = r / NN;
    half8 xv = *(const half8*)(x + (size_t)r*ldx + cg);
    half8 rv;
    if (res) rv = *(const half8*)(res + (size_t)r*ldr + cg);
    half8 ov;
    #pragma unroll
    for (int j = 0; j < 8; ++j) {
        int c = cg + j;
        float s1 = sums[(b*CC + c)*2], s2 = sums[(b*CC + c)*2 + 1];
        float mu  = s1 * (1.f/NN);
        float var = s2 * (1.f/NN) - mu*mu;
        float rstd = rsqrtf(var + 1e-6f);
        float y = ((float)xv[j] - mu) * rstd * scale[c] + bias[c];
        if (do_relu) y = fmaxf(y, 0.f);
        if (res) y += (float)rv[j];
        ov[j] = (h16)y;
    }
    *(half8*)(out + (size_t)r*ldo + cg) = ov;
}

// ---------------- f16 MFMA GEMM (NT) ----------------
template<int BN, bool OUT_F32, bool CSTAT>
__global__ __launch_bounds__(256) void pct_gemm_f16(
    const h16* __restrict__ A, int lda,
    const h16* __restrict__ WT, const float* __restrict__ bias,
    void* __restrict__ outp, int ldo, int K, const float* __restrict__ rowS,
    float* __restrict__ csums)
{
    constexpr int BJ = BN/2;
    constexpr int NF = BJ/16;
    __shared__ __align__(16) h16 Asm[128*64];
    __shared__ __align__(16) h16 Bsm[BN*64];
    const int tid = threadIdx.x;
    const int lane = tid & 63, w = tid >> 6;
    const int ln = lane & 15, lq = lane >> 4;
    const int wr = w >> 1, wc = w & 1;
    const int m0 = blockIdx.x*128, n0 = blockIdx.y*BN;
    f32x4 acc[4][NF];
    #pragma unroll
    for (int i = 0; i < 4; ++i)
        #pragma unroll
        for (int j = 0; j < NF; ++j) acc[i][j] = (f32x4){0.f,0.f,0.f,0.f};
    for (int k0 = 0; k0 < K; k0 += 64) {
        stage_rows<128>(A, lda, m0, k0, Asm, tid);
        stage_rows<BN>(WT, K, n0, k0, Bsm, tid);
        __syncthreads();
        #pragma unroll
        for (int kk = 0; kk < 2; ++kk) {
            half8 af[4], bfr[NF];
            #pragma unroll
            for (int i = 0; i < 4; ++i) af[i] = frag_ld(Asm, wr*64 + i*16 + ln, kk*4 + lq);
            #pragma unroll
            for (int j = 0; j < NF; ++j) bfr[j] = frag_ld(Bsm, wc*BJ + j*16 + ln, kk*4 + lq);
            #pragma unroll
            for (int i = 0; i < 4; ++i)
                #pragma unroll
                for (int j = 0; j < NF; ++j)
                    acc[i][j] = __builtin_amdgcn_mfma_f32_16x16x32_f16(af[i], bfr[j], acc[i][j], 0, 0, 0);
        }
        __syncthreads();
    }
    float cs1[NF], cs2[NF];
    #pragma unroll
    for (int j = 0; j < NF; ++j) {
        int col = n0 + wc*BJ + j*16 + ln;
        float bv = bias[col];
        float s1 = 0.f, s2 = 0.f;
        #pragma unroll
        for (int i = 0; i < 4; ++i) {
            #pragma unroll
            for (int r = 0; r < 4; ++r) {
                int row = m0 + wr*64 + i*16 + lq*4 + r;
                float sc = 1.f;
                if (rowS) { float s = rowS[row]; sc = s / (1e-9f + s); }
                float v = acc[i][j][r] * sc + bv;
                if (OUT_F32) ((float*)outp)[(size_t)row*ldo + col] = v;
                else ((h16*)outp)[(size_t)row*ldo + col] = (h16)v;
                if (CSTAT) { s1 += v; s2 += v*v; }
            }
        }
        cs1[j] = s1; cs2[j] = s2;
    }
    if constexpr (CSTAT) {
        __shared__ float cred[2][2][BJ][2];
        #pragma unroll
        for (int j = 0; j < NF; ++j) {
            float s1 = cs1[j], s2 = cs2[j];
            s1 += __shfl_down(s1, 16); s1 += __shfl_down(s1, 32);
            s2 += __shfl_down(s2, 16); s2 += __shfl_down(s2, 32);
            if (lane < 16) {
                cred[wr][wc][j*16 + lane][0] = s1;
                cred[wr][wc][j*16 + lane][1] = s2;
            }
        }
        __syncthreads();
        if (tid < 2*BN) {
            int c = tid >> 1, st = tid & 1;
            int wcc = c >> 5, ci = c & 31;
            float v = cred[0][wcc][ci][st] + cred[1][wcc][ci][st];
            int b = m0 >> 12;
            atomicAdd(&csums[((size_t)b*CC + n0 + c)*2 + st], v);
        }
    }
}

// ---------------- pass A: row max/sumexp2 of (log2e-scaled) Q@K^T ----------------
// 64 resident m-rows per wave (2 B-frag sets): each LDS A-fragment feeds TWO MFMAs.
// Wave (wn = w&1, wm = w>>1): n-coverage wn*64 + j*32 (j<2), m-coverage wm*64 + mh*32 (mh<2).
// K streamed via double-buffered LDS with counted vmcnt(4) (R6 discipline).
// part[] gains a wn-partial slot: index (m*SPL + sp)*2 + wn.
__global__ __launch_bounds__(256, 2) void attn_rowstats(const h16* __restrict__ QKV,
    float2* __restrict__ part)
{
    __shared__ __align__(16) h16 Ks[2][128*64];   // 32 KB
    const int b = blockIdx.x, mt = blockIdx.y, sp = blockIdx.z;
    const int tid = threadIdx.x;
    const int lane = tid & 63, w = tid >> 6;
    const int ln2 = lane & 31, h = lane >> 5;
    const int wn = w & 1, wm = w >> 1;
    const h16* qb = QKV + (size_t)b*NN*QKLD;
    const h16* kb = qb + CC;
    const int m0 = mt*128;
    half8 qreg[2][16];
    #pragma unroll
    for (int mh = 0; mh < 2; ++mh) {
        const h16* qrow = qb + (size_t)(m0 + wm*64 + mh*32 + ln2)*QKLD + h*8;
        #pragma unroll
        for (int i = 0; i < 16; ++i) qreg[mh][i] = *(const half8*)(qrow + i*16);
    }

    const int nbeg = sp*(NN/SPL);
    constexpr int NT = (NN/SPL)/128;      // 2 n-tiles -> 8 chunks
    constexpr int NCH = NT*4;
    float rm[2] = {NEG_BIG, NEG_BIG}, rs[2] = {0.f, 0.f};

    stage_rows<128>(kb, QKLD, nbeg, 0, Ks[0], tid);   // chunk 0
    int id = 0;
    #pragma unroll
    for (int t = 0; t < NT; ++t) {
        f32x16 acc[2][2];   // [j][mh]
        #pragma unroll
        for (int j = 0; j < 2; ++j)
            #pragma unroll
            for (int mh = 0; mh < 2; ++mh) acc[j][mh] = (f32x16)(0.f);
        #pragma unroll
        for (int c = 0; c < 4; ++c, ++id) {
            if (id + 1 < NCH) {
                stage_rows<128>(kb, QKLD, nbeg + ((id+1) >> 2)*128, ((id+1) & 3)*64,
                                Ks[(id+1) & 1], tid);
                WAITVM(4);            // chunk id landed; id+1 in flight
            } else {
                WAITVM(0);
            }
            __builtin_amdgcn_s_barrier();
            const h16* buf = Ks[id & 1];
            __builtin_amdgcn_s_setprio(1);
            #pragma unroll
            for (int kk = 0; kk < 4; ++kk) {
                half8 af[2];
                #pragma unroll
                for (int j = 0; j < 2; ++j)
                    af[j] = frag_ld(buf, wn*64 + j*32 + ln2, kk*2 + h);
                #pragma unroll
                for (int j = 0; j < 2; ++j)
                    #pragma unroll
                    for (int mh = 0; mh < 2; ++mh)
                        acc[j][mh] = __builtin_amdgcn_mfma_f32_32x32x16_f16(
                            af[j], qreg[mh][c*4 + kk], acc[j][mh], 0, 0, 0);
            }
            __builtin_amdgcn_s_setprio(0);
            __builtin_amdgcn_s_barrier();          // reads retired -> next stage may overwrite
        }
        #pragma unroll
        for (int mh = 0; mh < 2; ++mh) {
            float tm = NEG_BIG;
            #pragma unroll
            for (int j = 0; j < 2; ++j)
                #pragma unroll
                for (int g = 0; g < 16; g += 2)
                    tm = fmaxf(tm, fmaxf(acc[j][mh][g], acc[j][mh][g+1]));
            if (tm > rm[mh]) { rs[mh] *= exp2f(rm[mh] - tm); rm[mh] = tm; }
            float s = 0.f;
            #pragma unroll
            for (int j = 0; j < 2; ++j)
                #pragma unroll
                for (int g = 0; g < 16; ++g)
                    s += exp2f(acc[j][mh][g] - rm[mh]);
            rs[mh] += s;
        }
    }
    #pragma unroll
    for (int mh = 0; mh < 2; ++mh) {
        float mo = __shfl_xor(rm[mh], 32, 64);
        float so = __shfl_xor(rs[mh], 32, 64);
        float mn = fmaxf(rm[mh], mo);
        float sm = rs[mh]*exp2f(rm[mh] - mn) + so*exp2f(mo - mn);
        if (lane < 32) {
            int m = m0 + wm*64 + mh*32 + ln2;
            part[(((size_t)b*NN + m)*SPL + sp)*2 + wn] = make_float2(mn, sm);
        }
    }
}

// ---------------- pass B: column sums of softmax (row stats combined inline) ----------------
// 64 resident n-rows per wave (2 kreg sets); Q streamed. Wave (ws = w&1 picks the
// 64-m half of the staged chunk, wn2 = w>>1 picks the 64-n half of the block tile).
__global__ __launch_bounds__(256, 2) void attn_colsums(const h16* __restrict__ QKV,
    const float2* __restrict__ part, float* __restrict__ S)
{
    __shared__ __align__(16) h16 Qs[2][128*64];   // 32 KB
    __shared__ float2 rst_s[256];
    const int b = blockIdx.x, nt = blockIdx.y, sp = blockIdx.z;
    const int tid = threadIdx.x;
    const int lane = tid & 63, w = tid >> 6;
    const int ln2 = lane & 31, h = lane >> 5;
    const int ws = w & 1, wn2 = w >> 1;
    const h16* qb = QKV + (size_t)b*NN*QKLD;
    const h16* kb = qb + CC;
    const int n0 = nt*128;
    const int mbeg = sp*(NN/SPL);

    // inline rowcomb: combine SPL*2 partials for this block's 256 m-rows -> LDS
    {
        const float2* pp = part + ((size_t)b*NN + mbeg + tid)*SPL*2;
        float m = NEG_BIG;
        #pragma unroll
        for (int s = 0; s < SPL*2; ++s) m = fmaxf(m, pp[s].x);
        float sum = 0.f;
        #pragma unroll
        for (int s = 0; s < SPL*2; ++s) sum += pp[s].y * exp2f(pp[s].x - m);
        rst_s[tid] = make_float2(m, 1.0f / sum);
    }
    __syncthreads();   // full drain fine: no prefetch issued yet

    half8 kreg[2][16];
    #pragma unroll
    for (int nh = 0; nh < 2; ++nh) {
        const h16* krow = kb + (size_t)(n0 + wn2*64 + nh*32 + ln2)*QKLD + h*8;
        #pragma unroll
        for (int i = 0; i < 16; ++i) kreg[nh][i] = *(const half8*)(krow + i*16);
    }

    constexpr int NT = (NN/SPL)/128;
    constexpr int NCH = NT*4;
    float cs[2] = {0.f, 0.f};

    stage_rows<128>(qb, QKLD, mbeg, 0, Qs[0], tid);
    int id = 0;
    #pragma unroll
    for (int t = 0; t < NT; ++t) {
        f32x16 acc[2][2];   // [js][nh]
        #pragma unroll
        for (int js = 0; js < 2; ++js)
            #pragma unroll
            for (int nh = 0; nh < 2; ++nh) acc[js][nh] = (f32x16)(0.f);
        #pragma unroll
        for (int c = 0; c < 4; ++c, ++id) {
            if (id + 1 < NCH) {
                stage_rows<128>(qb, QKLD, mbeg + ((id+1) >> 2)*128, ((id+1) & 3)*64,
                                Qs[(id+1) & 1], tid);
                WAITVM(4);
            } else {
                WAITVM(0);
            }
            __builtin_amdgcn_s_barrier();
            const h16* buf = Qs[id & 1];
            __builtin_amdgcn_s_setprio(1);
            #pragma unroll
            for (int kk = 0; kk < 4; ++kk) {
                half8 af[2];
                #pragma unroll
                for (int js = 0; js < 2; ++js)
                    af[js] = frag_ld(buf, ws*64 + js*32 + ln2, kk*2 + h);
                #pragma unroll
                for (int js = 0; js < 2; ++js)
                    #pragma unroll
                    for (int nh = 0; nh < 2; ++nh)
                        acc[js][nh] = __builtin_amdgcn_mfma_f32_32x32x16_f16(
                            af[js], kreg[nh][c*4 + kk], acc[js][nh], 0, 0, 0);
            }
            __builtin_amdgcn_s_setprio(0);
            __builtin_amdgcn_s_barrier();
        }
        int mt0 = t*128;
        #pragma unroll
        for (int js = 0; js < 2; ++js) {
            #pragma unroll
            for (int nh = 0; nh < 2; ++nh) {
                #pragma unroll
                for (int g = 0; g < 16; ++g) {
                    int mloc = mt0 + ws*64 + js*32 + (g & 3) + 8*(g >> 2) + 4*h;
                    float2 st = rst_s[mloc];
                    cs[nh] += exp2f(acc[js][nh][g] - st.x) * st.y;
                }
            }
        }
    }
    #pragma unroll
    for (int nh = 0; nh < 2; ++nh) {
        cs[nh] += __shfl_xor(cs[nh], 32, 64);
        if (lane < 32) {
            int n = n0 + wn2*64 + nh*32 + ln2;
            atomicAdd(&S[(size_t)b*NN + n], cs[nh]);
        }
    }
}

extern "C" void kernel_launch(void* const* d_in, const int* in_sizes, int n_in,
                              void* d_out, int out_size, void* d_ws, size_t ws_size,
                              hipStream_t stream)
{
    const float* inp  = (const float*)d_in[0];
    const float* w0   = (const float*)d_in[1];
    const float* b0   = (const float*)d_in[2];
    const float* ln0s = (const float*)d_in[3];
    const float* ln0b = (const float*)d_in[4];
    const float* w1   = (const float*)d_in[5];
    const float* b1   = (const float*)d_in[6];
    const float* ln1s = (const float*)d_in[7];
    const float* ln1b = (const float*)d_in[8];
    const float* wq   = (const float*)d_in[9];
    const float* bq   = (const float*)d_in[10];
    const float* wk   = (const float*)d_in[11];
    const float* bk   = (const float*)d_in[12];
    const float* wv   = (const float*)d_in[13];
    const float* bv   = (const float*)d_in[14];
    const float* wo   = (const float*)d_in[15];
    const float* bo   = (const float*)d_in[16];
    const float* alns = (const float*)d_in[17];
    const float* alnb = (const float*)d_in[18];
    const float* wf   = (const float*)d_in[19];
    const float* bfb  = (const float*)d_in[20];
    float* out = (float*)d_out;

    // workspace layout
    char* p = (char*)d_ws;
    auto alloc = [&](size_t bytes) { char* r = p; p += (bytes + 255) & ~255ULL; return r; };
    h16* t0    = (h16*)alloc((size_t)RR*CC*2);
    h16* t1    = (h16*)alloc((size_t)RR*CC*2);
    h16* t2    = (h16*)alloc((size_t)RR*CC*2);
    h16* x1    = (h16*)alloc((size_t)RR*CC*2);
    h16* qkv   = (h16*)alloc((size_t)RR*QKLD*2);
    h16* oh    = (h16*)alloc((size_t)RR*CC*2);
    h16* xcat  = (h16*)alloc((size_t)RR*FF*2);
    h16* w1T   = (h16*)alloc((size_t)CC*CC*2);
    h16* wqkvT = (h16*)alloc((size_t)NLAYER*QKLD*CC*2);
    h16* woT   = (h16*)alloc((size_t)NLAYER*CC*CC*2);
    h16* wfT   = (h16*)alloc((size_t)FF*FF*2);
    float* bqkv  = (float*)alloc((size_t)NLAYER*QKLD*4);
    float2* part  = (float2*)alloc((size_t)RR*SPL*2*8);   // [m][sp][wn]
    float* Ssum  = (float*)alloc((size_t)NLAYER*RR*4);   // zeroed below
    float* lns   = (float*)alloc((size_t)6*BB*CC*2*4);   // zeroed below (adjacent)

    dim3 blk(256);

    // zero Ssum..lns span in one memset (adjacent in layout)
    hipMemsetAsync(Ssum, 0, (size_t)((char*)(lns + 6*BB*CC*2) - (char*)Ssum), stream);

    // weight transpose+convert (+pack q/k/v; q scaled by log2e)
    pct_wtrans<<<dim3(CC/32, CC/32, 1), blk, 0, stream>>>(w1, w1T, CC, CC, CC*CC, 1.f);
    pct_wtrans_qkv<<<dim3(CC/32, CC/32, 3*NLAYER), blk, 0, stream>>>(wq, wk, wv, wqkvT);
    pct_wtrans<<<dim3(CC/32, CC/32, NLAYER), blk, 0, stream>>>(wo, woT, CC, CC, CC*CC, 1.f);
    pct_wtrans<<<dim3(FF/32, FF/32, 1), blk, 0, stream>>>(wf, wfT, FF, FF, FF*FF, 1.f);
    pct_bias3<<<NLAYER, blk, 0, stream>>>(bq, bk, bv, bqkv);

    // pre-conv stack (embed has fused column stats)
    pct_embed<<<RR/64, blk, 0, stream>>>(inp, w0, b0, t0, lns + 0*BB*CC*2);
    pct_lnapply<<<RR/8, blk, 0, stream>>>(t0, CC, lns + 0*BB*CC*2, ln0s, ln0b, nullptr, 0, t1, CC, 0);
    pct_gemm_f16<64,false,true><<<dim3(RR/128, CC/64), blk, 0, stream>>>(
        t1, CC, w1T, b1, t2, CC, CC, nullptr, lns + 1*BB*CC*2);
    pct_lnapply<<<RR/8, blk, 0, stream>>>(t2, CC, lns + 1*BB*CC*2, ln1s, ln1b, nullptr, 0, x1, CC, 0);

    const h16* xin = x1; int ldx = CC;
    for (int i = 0; i < NLAYER; ++i) {
        // fused q/k/v GEMM -> qkv[RR][768]
        pct_gemm_f16<64,false,false><<<dim3(RR/128, QKLD/64), blk, 0, stream>>>(
            xin, ldx, wqkvT + (size_t)i*QKLD*CC, bqkv + i*QKLD, qkv, QKLD, CC, nullptr, nullptr);

        attn_rowstats<<<dim3(BB, NN/128, SPL), blk, 0, stream>>>(qkv, part);
        attn_colsums<<<dim3(BB, NN/128, SPL), blk, 0, stream>>>(qkv, part, Ssum + (size_t)i*RR);

        // wo GEMM on v (rows scaled by col[m] in epilogue) + fused column stats
        pct_gemm_f16<64,false,true><<<dim3(RR/128, CC/64), blk, 0, stream>>>(
            qkv + 2*CC, QKLD, woT + (size_t)i*CC*CC, bo + i*CC, oh, CC, CC,
            Ssum + (size_t)i*RR, lns + (2+i)*BB*CC*2);

        pct_lnapply<<<RR/8, blk, 0, stream>>>(oh, CC, lns + (2+i)*BB*CC*2, alns + i*CC, alnb + i*CC,
                                              xin, ldx, xcat + i*CC, FF, 1);
        xin = xcat + i*CC; ldx = FF;
    }

    pct_gemm_f16<128,true,false><<<dim3(RR/128, FF/128), blk, 0, stream>>>(
        xcat, FF, wfT, bfb, out, FF, FF, nullptr, nullptr);
}

// Round 9
// 492.252 us; speedup vs baseline: 1.2138x; 1.2138x over previous
//
#include <hip/hip_runtime.h>

#define BB 2
#define NN 4096
#define CC 256
#define FF 1024
#define NLAYER 4
#define RR (BB*NN)
#define SPL 16           // n/m split for attention passes
#define QKLD (3*CC)      // qkv packed row stride = 768
#define NEG_BIG (-1e30f)
#define LOG2E 1.44269504f

typedef _Float16 h16;
typedef __attribute__((ext_vector_type(8))) _Float16 half8;
typedef __attribute__((ext_vector_type(4))) float f32x4;
typedef __attribute__((ext_vector_type(16))) float f32x16;

#define WAITVM(n) asm volatile("s_waitcnt vmcnt(" #n ")" ::: "memory")

// ---------------- async global->LDS, 16B per lane ----------------
__device__ __forceinline__ void gload16(const h16* g, h16* l) {
    __builtin_amdgcn_global_load_lds((const __attribute__((address_space(1))) void*)g,
                                     (__attribute__((address_space(3))) void*)l, 16, 0, 0);
}

// stage ROWS x 64 h16 chunk into lds[ROWS][64] with piece-XOR swizzle (256 threads)
template<int ROWS>
__device__ __forceinline__ void stage_rows(const h16* __restrict__ src, int ld,
    int row0, int c0, h16* lds, int tid)
{
    int w = tid >> 6;
    #pragma unroll
    for (int t = 0; t < ROWS/32; ++t) {
        int slot = t*256 + tid;
        int row = slot >> 3;
        int pp  = slot & 7;
        int piece = pp ^ (row & 7);
        gload16(src + (size_t)(row0 + row)*ld + c0 + piece*8,
                lds + (t*256 + w*64)*8);    // wave-uniform base; HW adds lane*16B
    }
}

// read 8 contiguous h16 (logical k-piece pl) of LDS row
__device__ __forceinline__ half8 frag_ld(const h16* lds, int row, int pl) {
    return *(const half8*)(lds + row*64 + ((pl ^ (row & 7))*8));
}

// ---------------- weight transpose+convert: W[K,N] f32 -> WT[N,K] f16 ----------------
__global__ __launch_bounds__(256) void pct_wtrans(const float* __restrict__ W,
    h16* __restrict__ WT, int K, int N, int dstride, float scale)
{
    __shared__ h16 t[32][33];
    const float* Wl = W + (size_t)blockIdx.z*K*N;
    h16* WTl = WT + (size_t)blockIdx.z*dstride;
    int k0 = blockIdx.x*32, n0 = blockIdx.y*32;
    int tx = threadIdx.x & 31, ty = threadIdx.x >> 5;
    #pragma unroll
    for (int i = ty; i < 32; i += 8)
        t[i][tx] = (h16)(Wl[(size_t)(k0+i)*N + n0 + tx] * scale);
    __syncthreads();
    #pragma unroll
    for (int i = ty; i < 32; i += 8)
        WTl[(size_t)(n0+i)*K + k0 + tx] = t[tx][i];
}

// combined q/k/v transpose into packed [NLAYER][768][256]; q scaled by log2(e).
// Corner blocks (x==0,y==0) also pack the q/k/v biases into bqkv[NLAYER][768].
__global__ __launch_bounds__(256) void pct_wtrans_qkv(const float* __restrict__ wq,
    const float* __restrict__ wk, const float* __restrict__ wv,
    const float* __restrict__ bq, const float* __restrict__ bk, const float* __restrict__ bv,
    h16* __restrict__ WT, float* __restrict__ bqkv)
{
    __shared__ h16 t[32][33];
    int z = blockIdx.z;
    int which = z >> 2, layer = z & 3;          // NLAYER == 4
    const float* Wl = (which == 0 ? wq : which == 1 ? wk : wv) + (size_t)layer*CC*CC;
    h16* WTl = WT + (size_t)layer*QKLD*CC + (size_t)which*CC*CC;
    float scale = (which == 0) ? LOG2E : 1.0f;
    int k0 = blockIdx.x*32, n0 = blockIdx.y*32;
    int tx = threadIdx.x & 31, ty = threadIdx.x >> 5;
    #pragma unroll
    for (int i = ty; i < 32; i += 8)
        t[i][tx] = (h16)(Wl[(size_t)(k0+i)*CC + n0 + tx] * scale);
    if (blockIdx.x == 0 && blockIdx.y == 0) {
        const float* bsrc = (which == 0 ? bq : which == 1 ? bk : bv);
        bqkv[layer*QKLD + which*CC + threadIdx.x] = bsrc[layer*CC + threadIdx.x] * scale;
    }
    __syncthreads();
    #pragma unroll
    for (int i = ty; i < 32; i += 8)
        WTl[(size_t)(n0+i)*CC + k0 + tx] = t[tx][i];
}

// ---------------- fold LN0 into w1: W'_b[n,k] = A_{b,k} w1[k,n]; bias'_b[n] = b1[n] + sum_k B_{b,k} w1[k,n]
// A = rstd*scale, B = bias - mu*rstd*scale, from embed's column stats.
__global__ __launch_bounds__(256) void pct_wfold(const float* __restrict__ w1,
    const float* __restrict__ sums, const float* __restrict__ ls, const float* __restrict__ lb,
    const float* __restrict__ b1, h16* __restrict__ w1Tb, float* __restrict__ biasb)
{
    __shared__ h16 t[32][33];
    __shared__ float bb[8][32];
    int b = blockIdx.z;
    int k0 = blockIdx.x*32, n0 = blockIdx.y*32;
    int tx = threadIdx.x & 31, ty = threadIdx.x >> 5;
    float psum = 0.f;
    #pragma unroll
    for (int i = ty; i < 32; i += 8) {
        int k = k0 + i;
        float s1 = sums[(b*CC + k)*2], s2 = sums[(b*CC + k)*2 + 1];
        float mu  = s1 * (1.f/NN);
        float var = s2 * (1.f/NN) - mu*mu;
        float rstd = rsqrtf(var + 1e-6f);
        float A = rstd * ls[k];
        float Bv = lb[k] - mu * rstd * ls[k];
        float wv = w1[(size_t)k*CC + n0 + tx];
        t[i][tx] = (h16)(wv * A);
        psum += Bv * wv;
    }
    bb[ty][tx] = psum;
    __syncthreads();
    if (ty == 0) {
        float s = 0.f;
        #pragma unroll
        for (int r = 0; r < 8; ++r) s += bb[r][tx];
        if (k0 == 0) s += b1[n0 + tx];
        atomicAdd(&biasb[b*CC + n0 + tx], s);
    }
    #pragma unroll
    for (int i = ty; i < 32; i += 8)
        w1Tb[(size_t)b*CC*CC + (size_t)(n0+i)*CC + k0 + tx] = t[tx][i];
}

// ---------------- embed + fused column stats ----------------
__global__ __launch_bounds__(256) void pct_embed(const float* __restrict__ inp,
    const float* __restrict__ w0, const float* __restrict__ b0,
    h16* __restrict__ out, float* __restrict__ sums)
{
    int c = threadIdx.x;
    int r0 = blockIdx.x * 64;
    float wa = w0[c], wb = w0[CC+c], wcv = w0[2*CC+c], bb = b0[c];
    float s1 = 0.f, s2 = 0.f;
    #pragma unroll 4
    for (int i = 0; i < 64; ++i) {
        int r = r0 + i;
        float y = bb + inp[r*3+0]*wa + inp[r*3+1]*wb + inp[r*3+2]*wcv;
        h16 hy = (h16)y;
        out[(size_t)r*CC + c] = hy;
        float yf = (float)hy;
        s1 += yf; s2 += yf*yf;
    }
    int b = r0 >> 12;
    atomicAdd(&sums[((size_t)b*CC + c)*2 + 0], s1);
    atomicAdd(&sums[((size_t)b*CC + c)*2 + 1], s2);
}

// ---------------- apply LN (stats over points), optional relu + residual ----------------
__global__ __launch_bounds__(256) void pct_lnapply(const h16* __restrict__ x, int ldx,
    const float* __restrict__ sums, const float* __restrict__ scale, const float* __restrict__ bias,
    const h16* __restrict__ res, int ldr, h16* __restrict__ out, int ldo,
    int do_relu)
{
    int r = blockIdx.x*8 + (threadIdx.x >> 5);
    int cg = (threadIdx.x & 31) * 8;
    int b = r / NN;
    half8 xv = *(const half8*)(x + (size_t)r*ldx + cg);
    half8 rv;
    if (res) rv = *(const half8*)(res + (size_t)r*ldr + cg);
    half8 ov;
    #pragma unroll
    for (int j = 0; j < 8; ++j) {
        int c = cg + j;
        float s1 = sums[(b*CC + c)*2], s2 = sums[(b*CC + c)*2 + 1];
        float mu  = s1 * (1.f/NN);
        float var = s2 * (1.f/NN) - mu*mu;
        float rstd = rsqrtf(var + 1e-6f);
        float y = ((float)xv[j] - mu) * rstd * scale[c] + bias[c];
        if (do_relu) y = fmaxf(y, 0.f);
        if (res) y += (float)rv[j];
        ov[j] = (h16)y;
    }
    *(half8*)(out + (size_t)r*ldo + cg) = ov;
}

// ---------------- f16 MFMA GEMM (NT); per-batch weight/bias strides wbs/bbs ----------------
template<int BN, bool OUT_F32, bool CSTAT>
__global__ __launch_bounds__(256) void pct_gemm_f16(
    const h16* __restrict__ A, int lda,
    const h16* __restrict__ WT, const float* __restrict__ bias,
    void* __restrict__ outp, int ldo, int K, const float* __restrict__ rowS,
    float* __restrict__ csums, int wbs, int bbs)
{
    constexpr int BJ = BN/2;
    constexpr int NF = BJ/16;
    __shared__ __align__(16) h16 Asm[128*64];
    __shared__ __align__(16) h16 Bsm[BN*64];
    const int tid = threadIdx.x;
    const int lane = tid & 63, w = tid >> 6;
    const int ln = lane & 15, lq = lane >> 4;
    const int wr = w >> 1, wc = w & 1;
    const int m0 = blockIdx.x*128, n0 = blockIdx.y*BN;
    WT   += (size_t)(m0 >> 12) * wbs;
    bias += (size_t)(m0 >> 12) * bbs;
    f32x4 acc[4][NF];
    #pragma unroll
    for (int i = 0; i < 4; ++i)
        #pragma unroll
        for (int j = 0; j < NF; ++j) acc[i][j] = (f32x4){0.f,0.f,0.f,0.f};
    for (int k0 = 0; k0 < K; k0 += 64) {
        stage_rows<128>(A, lda, m0, k0, Asm, tid);
        stage_rows<BN>(WT, K, n0, k0, Bsm, tid);
        __syncthreads();
        #pragma unroll
        for (int kk = 0; kk < 2; ++kk) {
            half8 af[4], bfr[NF];
            #pragma unroll
            for (int i = 0; i < 4; ++i) af[i] = frag_ld(Asm, wr*64 + i*16 + ln, kk*4 + lq);
            #pragma unroll
            for (int j = 0; j < NF; ++j) bfr[j] = frag_ld(Bsm, wc*BJ + j*16 + ln, kk*4 + lq);
            #pragma unroll
            for (int i = 0; i < 4; ++i)
                #pragma unroll
                for (int j = 0; j < NF; ++j)
                    acc[i][j] = __builtin_amdgcn_mfma_f32_16x16x32_f16(af[i], bfr[j], acc[i][j], 0, 0, 0);
        }
        __syncthreads();
    }
    float cs1[NF], cs2[NF];
    #pragma unroll
    for (int j = 0; j < NF; ++j) {
        int col = n0 + wc*BJ + j*16 + ln;
        float bv = bias[col];
        float s1 = 0.f, s2 = 0.f;
        #pragma unroll
        for (int i = 0; i < 4; ++i) {
            #pragma unroll
            for (int r = 0; r < 4; ++r) {
                int row = m0 + wr*64 + i*16 + lq*4 + r;
                float sc = 1.f;
                if (rowS) { float s = rowS[row]; sc = s / (1e-9f + s); }
                float v = acc[i][j][r] * sc + bv;
                if (OUT_F32) ((float*)outp)[(size_t)row*ldo + col] = v;
                else ((h16*)outp)[(size_t)row*ldo + col] = (h16)v;
                if (CSTAT) { s1 += v; s2 += v*v; }
            }
        }
        cs1[j] = s1; cs2[j] = s2;
    }
    if constexpr (CSTAT) {
        __shared__ float cred[2][2][BJ][2];
        #pragma unroll
        for (int j = 0; j < NF; ++j) {
            float s1 = cs1[j], s2 = cs2[j];
            s1 += __shfl_down(s1, 16); s1 += __shfl_down(s1, 32);
            s2 += __shfl_down(s2, 16); s2 += __shfl_down(s2, 32);
            if (lane < 16) {
                cred[wr][wc][j*16 + lane][0] = s1;
                cred[wr][wc][j*16 + lane][1] = s2;
            }
        }
        __syncthreads();
        if (tid < 2*BN) {
            int c = tid >> 1, st = tid & 1;
            int wcc = c >> 5, ci = c & 31;
            float v = cred[0][wcc][ci][st] + cred[1][wcc][ci][st];
            int b = m0 >> 12;
            atomicAdd(&csums[((size_t)b*CC + n0 + c)*2 + st], v);
        }
    }
}

// ---------------- pass A: row max/sumexp2 of (log2e-scaled) Q@K^T ----------------
// Q resident in regs; K streamed via DOUBLE-buffered LDS (32 KB -> 4 blocks/CU).
// Counted vmcnt(4): stage(id+1) in flight across barrier. [R6 structure, 497.6 us]
__global__ __launch_bounds__(256) void attn_rowstats(const h16* __restrict__ QKV,
    float2* __restrict__ part)
{
    __shared__ __align__(16) h16 Ks[2][128*64];   // 32 KB
    const int b = blockIdx.x, mt = blockIdx.y, sp = blockIdx.z;
    const int tid = threadIdx.x;
    const int lane = tid & 63, w = tid >> 6;
    const int ln2 = lane & 31, h = lane >> 5;
    const h16* qb = QKV + (size_t)b*NN*QKLD;
    const h16* kb = qb + CC;
    const int m0 = mt*128;
    const h16* qrow = qb + (size_t)(m0 + w*32 + ln2)*QKLD + h*8;
    half8 qreg[16];
    #pragma unroll
    for (int i = 0; i < 16; ++i) qreg[i] = *(const half8*)(qrow + i*16);

    const int nbeg = sp*(NN/SPL);
    constexpr int NT = (NN/SPL)/128;      // 2 n-tiles -> 8 chunks
    constexpr int NCH = NT*4;
    float rm = NEG_BIG, rs = 0.f;

    stage_rows<128>(kb, QKLD, nbeg, 0, Ks[0], tid);   // chunk 0
    int id = 0;
    #pragma unroll
    for (int t = 0; t < NT; ++t) {
        f32x16 acc[4];
        #pragma unroll
        for (int j = 0; j < 4; ++j) acc[j] = (f32x16)(0.f);
        #pragma unroll
        for (int c = 0; c < 4; ++c, ++id) {
            if (id + 1 < NCH) {
                stage_rows<128>(kb, QKLD, nbeg + ((id+1) >> 2)*128, ((id+1) & 3)*64,
                                Ks[(id+1) & 1], tid);
                WAITVM(4);            // FIFO [id:4][id+1:4] -> chunk id landed, id+1 in flight
            } else {
                WAITVM(0);
            }
            __builtin_amdgcn_s_barrier();          // all waves' chunk-id loads landed
            const h16* buf = Ks[id & 1];
            __builtin_amdgcn_s_setprio(1);
            #pragma unroll
            for (int kk = 0; kk < 4; ++kk) {
                half8 bq = qreg[c*4 + kk];
                #pragma unroll
                for (int j = 0; j < 4; ++j) {
                    half8 af = frag_ld(buf, j*32 + ln2, kk*2 + h);
                    acc[j] = __builtin_amdgcn_mfma_f32_32x32x16_f16(af, bq, acc[j], 0, 0, 0);
                }
            }
            __builtin_amdgcn_s_setprio(0);
            __builtin_amdgcn_s_barrier();          // reads of buf retired -> next stage may overwrite
        }
        float tm = NEG_BIG;
        #pragma unroll
        for (int j = 0; j < 4; ++j)
            #pragma unroll
            for (int g = 0; g < 16; g += 2)
                tm = fmaxf(tm, fmaxf(acc[j][g], acc[j][g+1]));
        if (tm > rm) { rs *= exp2f(rm - tm); rm = tm; }
        float s = 0.f;
        #pragma unroll
        for (int j = 0; j < 4; ++j)
            #pragma unroll
            for (int g = 0; g < 16; ++g)
                s += exp2f(acc[j][g] - rm);
        rs += s;
    }
    float mo = __shfl_xor(rm, 32, 64);
    float so = __shfl_xor(rs, 32, 64);
    float mn = fmaxf(rm, mo);
    float sm = rs*exp2f(rm - mn) + so*exp2f(mo - mn);
    if (lane < 32) {
        int m = m0 + w*32 + ln2;
        part[((size_t)b*NN + m)*SPL + sp] = make_float2(mn, sm);
    }
}

// ---------------- pass B: column sums of softmax (row stats combined inline) ----------------
__global__ __launch_bounds__(256) void attn_colsums(const h16* __restrict__ QKV,
    const float2* __restrict__ part, float* __restrict__ S)
{
    __shared__ __align__(16) h16 Qs[2][128*64];   // 32 KB
    __shared__ float2 rst_s[256];
    const int b = blockIdx.x, nt = blockIdx.y, sp = blockIdx.z;
    const int tid = threadIdx.x;
    const int lane = tid & 63, w = tid >> 6;
    const int ln2 = lane & 31, h = lane >> 5;
    const h16* qb = QKV + (size_t)b*NN*QKLD;
    const h16* kb = qb + CC;
    const int n0 = nt*128;
    const int mbeg = sp*(NN/SPL);

    // inline rowcomb: combine SPL partials for this block's 256 m-rows -> LDS
    {
        const float2* pp = part + ((size_t)b*NN + mbeg + tid)*SPL;
        float m = NEG_BIG;
        #pragma unroll
        for (int s = 0; s < SPL; ++s) m = fmaxf(m, pp[s].x);
        float sum = 0.f;
        #pragma unroll
        for (int s = 0; s < SPL; ++s) sum += pp[s].y * exp2f(pp[s].x - m);
        rst_s[tid] = make_float2(m, 1.0f / sum);
    }
    __syncthreads();   // full drain fine: no prefetch issued yet

    const h16* krow = kb + (size_t)(n0 + w*32 + ln2)*QKLD + h*8;
    half8 kreg[16];
    #pragma unroll
    for (int i = 0; i < 16; ++i) kreg[i] = *(const half8*)(krow + i*16);

    constexpr int NT = (NN/SPL)/128;
    constexpr int NCH = NT*4;
    float cs = 0.f;

    stage_rows<128>(qb, QKLD, mbeg, 0, Qs[0], tid);
    int id = 0;
    #pragma unroll
    for (int t = 0; t < NT; ++t) {
        f32x16 acc[4];
        #pragma unroll
        for (int j = 0; j < 4; ++j) acc[j] = (f32x16)(0.f);
        #pragma unroll
        for (int c = 0; c < 4; ++c, ++id) {
            if (id + 1 < NCH) {
                stage_rows<128>(qb, QKLD, mbeg + ((id+1) >> 2)*128, ((id+1) & 3)*64,
                                Qs[(id+1) & 1], tid);
                WAITVM(4);
            } else {
                WAITVM(0);
            }
            __builtin_amdgcn_s_barrier();
            const h16* buf = Qs[id & 1];
            __builtin_amdgcn_s_setprio(1);
            #pragma unroll
            for (int kk = 0; kk < 4; ++kk) {
                half8 bk = kreg[c*4 + kk];
                #pragma unroll
                for (int j = 0; j < 4; ++j) {
                    half8 af = frag_ld(buf, j*32 + ln2, kk*2 + h);
                    acc[j] = __builtin_amdgcn_mfma_f32_32x32x16_f16(af, bk, acc[j], 0, 0, 0);
                }
            }
            __builtin_amdgcn_s_setprio(0);
            __builtin_amdgcn_s_barrier();
        }
        int mt0 = t*128;
        #pragma unroll
        for (int j = 0; j < 4; ++j) {
            #pragma unroll
            for (int g = 0; g < 16; ++g) {
                int mloc = mt0 + j*32 + (g & 3) + 8*(g >> 2) + 4*h;
                float2 st = rst_s[mloc];
                cs += exp2f(acc[j][g] - st.x) * st.y;
            }
        }
    }
    cs += __shfl_xor(cs, 32, 64);
    if (lane < 32) {
        int n = n0 + w*32 + ln2;
        atomicAdd(&S[(size_t)b*NN + n], cs);
    }
}

extern "C" void kernel_launch(void* const* d_in, const int* in_sizes, int n_in,
                              void* d_out, int out_size, void* d_ws, size_t ws_size,
                              hipStream_t stream)
{
    const float* inp  = (const float*)d_in[0];
    const float* w0   = (const float*)d_in[1];
    const float* b0   = (const float*)d_in[2];
    const float* ln0s = (const float*)d_in[3];
    const float* ln0b = (const float*)d_in[4];
    const float* w1   = (const float*)d_in[5];
    const float* b1   = (const float*)d_in[6];
    const float* ln1s = (const float*)d_in[7];
    const float* ln1b = (const float*)d_in[8];
    const float* wq   = (const float*)d_in[9];
    const float* bq   = (const float*)d_in[10];
    const float* wk   = (const float*)d_in[11];
    const float* bk   = (const float*)d_in[12];
    const float* wv   = (const float*)d_in[13];
    const float* bv   = (const float*)d_in[14];
    const float* wo   = (const float*)d_in[15];
    const float* bo   = (const float*)d_in[16];
    const float* alns = (const float*)d_in[17];
    const float* alnb = (const float*)d_in[18];
    const float* wf   = (const float*)d_in[19];
    const float* bfb  = (const float*)d_in[20];
    float* out = (float*)d_out;

    // workspace layout
    char* p = (char*)d_ws;
    auto alloc = [&](size_t bytes) { char* r = p; p += (bytes + 255) & ~255ULL; return r; };
    h16* t0    = (h16*)alloc((size_t)RR*CC*2);
    h16* t2    = (h16*)alloc((size_t)RR*CC*2);
    h16* x1    = (h16*)alloc((size_t)RR*CC*2);
    h16* qkv   = (h16*)alloc((size_t)RR*QKLD*2);
    h16* oh    = (h16*)alloc((size_t)RR*CC*2);
    h16* xcat  = (h16*)alloc((size_t)RR*FF*2);
    h16* w1Tb  = (h16*)alloc((size_t)BB*CC*CC*2);   // per-batch LN0-folded w1
    h16* wqkvT = (h16*)alloc((size_t)NLAYER*QKLD*CC*2);
    h16* woT   = (h16*)alloc((size_t)NLAYER*CC*CC*2);
    h16* wfT   = (h16*)alloc((size_t)FF*FF*2);
    float* bqkv  = (float*)alloc((size_t)NLAYER*QKLD*4);
    float2* part  = (float2*)alloc((size_t)RR*SPL*8);
    float* Ssum  = (float*)alloc((size_t)NLAYER*RR*4);   // zeroed below
    float* lns   = (float*)alloc((size_t)6*BB*CC*2*4);   // zeroed below (adjacent)
    float* biasb = (float*)alloc((size_t)BB*CC*4);       // zeroed below (adjacent)

    dim3 blk(256);

    // zero Ssum..biasb span in one memset (adjacent in layout)
    hipMemsetAsync(Ssum, 0, (size_t)((char*)(biasb + BB*CC) - (char*)Ssum), stream);

    // weight transpose+convert (+pack q/k/v with biases; q scaled by log2e)
    pct_wtrans_qkv<<<dim3(CC/32, CC/32, 3*NLAYER), blk, 0, stream>>>(
        wq, wk, wv, bq, bk, bv, wqkvT, bqkv);
    pct_wtrans<<<dim3(CC/32, CC/32, NLAYER), blk, 0, stream>>>(wo, woT, CC, CC, CC*CC, 1.f);
    pct_wtrans<<<dim3(FF/32, FF/32, 1), blk, 0, stream>>>(wf, wfT, FF, FF, FF*FF, 1.f);

    // pre-conv stack: embed (fused column stats) -> fold LN0 into w1 -> w1 GEMM on raw t0
    pct_embed<<<RR/64, blk, 0, stream>>>(inp, w0, b0, t0, lns + 0*BB*CC*2);
    pct_wfold<<<dim3(CC/32, CC/32, BB), blk, 0, stream>>>(
        w1, lns + 0*BB*CC*2, ln0s, ln0b, b1, w1Tb, biasb);
    pct_gemm_f16<64,false,true><<<dim3(RR/128, CC/64), blk, 0, stream>>>(
        t0, CC, w1Tb, biasb, t2, CC, CC, nullptr, lns + 1*BB*CC*2, CC*CC, CC);
    pct_lnapply<<<RR/8, blk, 0, stream>>>(t2, CC, lns + 1*BB*CC*2, ln1s, ln1b, nullptr, 0, x1, CC, 0);

    const h16* xin = x1; int ldx = CC;
    for (int i = 0; i < NLAYER; ++i) {
        // fused q/k/v GEMM -> qkv[RR][768]
        pct_gemm_f16<64,false,false><<<dim3(RR/128, QKLD/64), blk, 0, stream>>>(
            xin, ldx, wqkvT + (size_t)i*QKLD*CC, bqkv + i*QKLD, qkv, QKLD, CC, nullptr, nullptr, 0, 0);

        attn_rowstats<<<dim3(BB, NN/128, SPL), blk, 0, stream>>>(qkv, part);
        attn_colsums<<<dim3(BB, NN/128, SPL), blk, 0, stream>>>(qkv, part, Ssum + (size_t)i*RR);

        // wo GEMM on v (rows scaled by col[m] in epilogue) + fused column stats
        pct_gemm_f16<64,false,true><<<dim3(RR/128, CC/64), blk, 0, stream>>>(
            qkv + 2*CC, QKLD, woT + (size_t)i*CC*CC, bo + i*CC, oh, CC, CC,
            Ssum + (size_t)i*RR, lns + (2+i)*BB*CC*2, 0, 0);

        pct_lnapply<<<RR/8, blk, 0, stream>>>(oh, CC, lns + (2+i)*BB*CC*2, alns + i*CC, alnb + i*CC,
                                              xin, ldx, xcat + i*CC, FF, 1);
        xin = xcat + i*CC; ldx = FF;
    }

    pct_gemm_f16<128,true,false><<<dim3(RR/128, FF/128), blk, 0, stream>>>(
        xcat, FF, wfT, bfb, out, FF, FF, nullptr, nullptr, 0, 0);
}